// Round 1
// baseline (416.955 us; speedup 1.0000x reference)
//
#include <hip/hip_runtime.h>
#include <math.h>

#define FSZ 2048
#define NTILES 16384
#define BATCH 16
#define RSEL 5

// ---------------------------------------------------------------------------
// Kernel 1: scores[t] = dot(feats[t, 0:2048], w_conv)   for t in [0, B*NTILES)
// Wave-per-tile; float4 coalesced loads; w_conv staged in LDS; grid-stride.
// ---------------------------------------------------------------------------
__global__ __launch_bounds__(256) void score_kernel(
    const float* __restrict__ feats,
    const float* __restrict__ w_conv,
    float* __restrict__ scores,
    int total_tiles)
{
    __shared__ float4 wsh[FSZ / 4];  // 8 KB
    const float4* w4 = reinterpret_cast<const float4*>(w_conv);
    for (int i = threadIdx.x; i < FSZ / 4; i += blockDim.x) wsh[i] = w4[i];
    __syncthreads();

    const int lane          = threadIdx.x & 63;
    const int wave          = threadIdx.x >> 6;
    const int wavesPerBlock = blockDim.x >> 6;
    const int globalWave    = blockIdx.x * wavesPerBlock + wave;
    const int totalWaves    = gridDim.x * wavesPerBlock;

    for (int tile = globalWave; tile < total_tiles; tile += totalWaves) {
        const float4* f4 = reinterpret_cast<const float4*>(feats + (size_t)tile * FSZ);
        float acc = 0.f;
#pragma unroll
        for (int k = 0; k < 8; ++k) {
            float4 a = f4[lane + 64 * k];
            float4 w = wsh[lane + 64 * k];
            acc += a.x * w.x + a.y * w.y + a.z * w.z + a.w * w.w;
        }
#pragma unroll
        for (int off = 32; off > 0; off >>= 1)
            acc += __shfl_xor(acc, off, 64);
        if (lane == 0) scores[tile] = acc;
    }
}

// ---------------------------------------------------------------------------
// Kernel 2: per batch row, 5 smallest (ascending) and 5 largest; write
// minmax[b][0:5]  = bottom-5 ascending   (== sort(scores)[:5])
// minmax[b][5:10] = top-5 ascending      (== sort(scores)[-5:])
// ---------------------------------------------------------------------------
__global__ __launch_bounds__(256) void select_kernel(
    const float* __restrict__ scores,
    float* __restrict__ minmax)
{
    const int b   = blockIdx.x;
    const int tid = threadIdx.x;
    const float* s = scores + b * NTILES;

    float mn[RSEL], mx[RSEL];  // mn ascending, mx descending
#pragma unroll
    for (int i = 0; i < RSEL; ++i) { mn[i] = INFINITY; mx[i] = -INFINITY; }

    for (int t = tid; t < NTILES; t += 256) {
        float v = s[t];
        if (v < mn[RSEL - 1]) {
            mn[RSEL - 1] = v;
#pragma unroll
            for (int i = RSEL - 1; i > 0; --i)
                if (mn[i] < mn[i - 1]) { float tmp = mn[i]; mn[i] = mn[i - 1]; mn[i - 1] = tmp; }
        }
        if (v > mx[RSEL - 1]) {
            mx[RSEL - 1] = v;
#pragma unroll
            for (int i = RSEL - 1; i > 0; --i)
                if (mx[i] > mx[i - 1]) { float tmp = mx[i]; mx[i] = mx[i - 1]; mx[i - 1] = tmp; }
        }
    }

    __shared__ float smn[256][RSEL];
    __shared__ float smx[256][RSEL];
#pragma unroll
    for (int i = 0; i < RSEL; ++i) { smn[tid][i] = mn[i]; smx[tid][i] = mx[i]; }

    for (int stride = 128; stride > 0; stride >>= 1) {
        __syncthreads();
        if (tid < stride) {
            float amn[RSEL], bmn[RSEL], omn[RSEL];
            float amx[RSEL], bmx[RSEL], omx[RSEL];
#pragma unroll
            for (int i = 0; i < RSEL; ++i) {
                amn[i] = smn[tid][i];  bmn[i] = smn[tid + stride][i];
                amx[i] = smx[tid][i];  bmx[i] = smx[tid + stride][i];
            }
            // 2-pointer merges: at step i, ia+ib == i <= RSEL-1, so always in-bounds
            int ia = 0, ib = 0;
#pragma unroll
            for (int i = 0; i < RSEL; ++i)
                omn[i] = (amn[ia] <= bmn[ib]) ? amn[ia++] : bmn[ib++];
            ia = 0; ib = 0;
#pragma unroll
            for (int i = 0; i < RSEL; ++i)
                omx[i] = (amx[ia] >= bmx[ib]) ? amx[ia++] : bmx[ib++];
#pragma unroll
            for (int i = 0; i < RSEL; ++i) { smn[tid][i] = omn[i]; smx[tid][i] = omx[i]; }
        }
    }
    __syncthreads();
    if (tid == 0) {
#pragma unroll
        for (int i = 0; i < RSEL; ++i) {
            minmax[b * 2 * RSEL + i]        = smn[0][i];            // bottom-5 ascending
            minmax[b * 2 * RSEL + RSEL + i] = smx[0][RSEL - 1 - i]; // top-5 ascending
        }
    }
}

// ---------------------------------------------------------------------------
// Kernel 3: tiny MLP  10 -> 200 -> sigmoid -> 100 -> sigmoid -> 1 -> sigmoid
// out[0:16] = logits, out[16:32] = probs  (tuple concat order)
// ---------------------------------------------------------------------------
__global__ __launch_bounds__(256) void mlp_kernel(
    const float* __restrict__ minmax,
    const float* __restrict__ W1, const float* __restrict__ b1,
    const float* __restrict__ W2, const float* __restrict__ b2,
    const float* __restrict__ W3, const float* __restrict__ b3,
    float* __restrict__ out)
{
    const int b   = blockIdx.x;
    const int tid = threadIdx.x;
    __shared__ float x[2 * RSEL];
    __shared__ float h1[200];
    __shared__ float h2[100];

    if (tid < 2 * RSEL) x[tid] = minmax[b * 2 * RSEL + tid];
    __syncthreads();

    if (tid < 200) {
        float acc = b1[tid];
#pragma unroll
        for (int i = 0; i < 2 * RSEL; ++i) acc += W1[tid * 2 * RSEL + i] * x[i];
        h1[tid] = 1.f / (1.f + expf(-acc));
    }
    __syncthreads();

    if (tid < 100) {
        float acc = b2[tid];
        for (int i = 0; i < 200; ++i) acc += W2[tid * 200 + i] * h1[i];
        h2[tid] = 1.f / (1.f + expf(-acc));
    }
    __syncthreads();

    if (tid == 0) {
        float acc = b3[0];
        for (int i = 0; i < 100; ++i) acc += W3[i] * h2[i];
        out[b]         = acc;                        // logits
        out[BATCH + b] = 1.f / (1.f + expf(-acc));   // probs
    }
}

extern "C" void kernel_launch(void* const* d_in, const int* in_sizes, int n_in,
                              void* d_out, int out_size, void* d_ws, size_t ws_size,
                              hipStream_t stream)
{
    const float* feats  = (const float*)d_in[0];
    const float* w_conv = (const float*)d_in[1];
    const float* W1     = (const float*)d_in[2];
    const float* b1     = (const float*)d_in[3];
    const float* W2     = (const float*)d_in[4];
    const float* b2     = (const float*)d_in[5];
    const float* W3     = (const float*)d_in[6];
    const float* b3     = (const float*)d_in[7];
    float* out = (float*)d_out;

    float* scores = (float*)d_ws;                       // B*NTILES floats = 1 MB
    float* minmax = scores + (size_t)BATCH * NTILES;    // B*10 floats

    const int total_tiles = BATCH * NTILES;
    score_kernel<<<2048, 256, 0, stream>>>(feats, w_conv, scores, total_tiles);
    select_kernel<<<BATCH, 256, 0, stream>>>(scores, minmax);
    mlp_kernel<<<BATCH, 256, 0, stream>>>(minmax, W1, b1, W2, b2, W3, b3, out);
}

// Round 2
// 358.783 us; speedup vs baseline: 1.1621x; 1.1621x over previous
//
#include <hip/hip_runtime.h>
#include <math.h>

#define FSZ 2048
#define NTILES 16384
#define BATCH 16
#define RSEL 5

typedef float f32x4 __attribute__((ext_vector_type(4)));

// ---------------------------------------------------------------------------
// Kernel 1: scores[t] = dot(feats[t, :], w_conv), wave-per-tile, 2 tiles/iter.
// w_conv held in 8 float4 registers per lane (lane i needs w[4i + 256k] only).
// Nontemporal feats loads (streamed once). 16 outstanding dwordx4 per lane.
// ---------------------------------------------------------------------------
__global__ __launch_bounds__(256) void score_kernel(
    const float* __restrict__ feats,
    const float* __restrict__ w_conv,
    float* __restrict__ scores,
    int total_tiles)
{
    const int lane       = threadIdx.x & 63;
    const int wave       = threadIdx.x >> 6;
    const int globalWave = blockIdx.x * 4 + wave;
    const int totalWaves = gridDim.x * 4;

    // w fragment in registers: lane holds w[lane*4 + 256k .. +3], k = 0..7
    const f32x4* w4 = reinterpret_cast<const f32x4*>(w_conv);
    f32x4 wreg[8];
#pragma unroll
    for (int k = 0; k < 8; ++k) wreg[k] = w4[lane + 64 * k];

    // total_tiles is even; pair (t, t+1) with stride 2*totalWaves covers all
    for (int t = globalWave * 2; t < total_tiles; t += 2 * totalWaves) {
        const f32x4* fa = reinterpret_cast<const f32x4*>(feats + (size_t)t * FSZ);
        const f32x4* fb = fa + FSZ / 4;

        float acca = 0.f, accb = 0.f;
#pragma unroll
        for (int k = 0; k < 8; ++k) {
            f32x4 a = __builtin_nontemporal_load(fa + lane + 64 * k);
            acca += a.x * wreg[k].x + a.y * wreg[k].y + a.z * wreg[k].z + a.w * wreg[k].w;
        }
#pragma unroll
        for (int k = 0; k < 8; ++k) {
            f32x4 b = __builtin_nontemporal_load(fb + lane + 64 * k);
            accb += b.x * wreg[k].x + b.y * wreg[k].y + b.z * wreg[k].z + b.w * wreg[k].w;
        }
#pragma unroll
        for (int off = 32; off > 0; off >>= 1) {
            acca += __shfl_xor(acca, off, 64);
            accb += __shfl_xor(accb, off, 64);
        }
        if (lane == 0) {
            scores[t]     = acca;
            scores[t + 1] = accb;
        }
    }
}

// ---------------------------------------------------------------------------
// Kernel 2 (fused select + MLP): block b finds bottom-5 / top-5 of row b,
// then runs the tiny MLP for row b in the same block.
// minmax[0:5] = sort(scores)[:5]; minmax[5:10] = sort(scores)[-5:]
// out[0:16] = logits, out[16:32] = probs (tuple concat order)
// ---------------------------------------------------------------------------
__global__ __launch_bounds__(256) void select_mlp_kernel(
    const float* __restrict__ scores,
    const float* __restrict__ W1, const float* __restrict__ b1,
    const float* __restrict__ W2, const float* __restrict__ b2,
    const float* __restrict__ W3, const float* __restrict__ b3,
    float* __restrict__ out)
{
    const int b   = blockIdx.x;
    const int tid = threadIdx.x;
    const f32x4* s4 = reinterpret_cast<const f32x4*>(scores + b * NTILES);

    float mn[RSEL], mx[RSEL];  // mn ascending, mx descending
#pragma unroll
    for (int i = 0; i < RSEL; ++i) { mn[i] = INFINITY; mx[i] = -INFINITY; }

    for (int t = tid; t < NTILES / 4; t += 256) {
        f32x4 v4 = s4[t];
#pragma unroll
        for (int j = 0; j < 4; ++j) {
            float v = v4[j];
            if (v < mn[RSEL - 1]) {
                mn[RSEL - 1] = v;
#pragma unroll
                for (int i = RSEL - 1; i > 0; --i)
                    if (mn[i] < mn[i - 1]) { float tmp = mn[i]; mn[i] = mn[i - 1]; mn[i - 1] = tmp; }
            }
            if (v > mx[RSEL - 1]) {
                mx[RSEL - 1] = v;
#pragma unroll
                for (int i = RSEL - 1; i > 0; --i)
                    if (mx[i] > mx[i - 1]) { float tmp = mx[i]; mx[i] = mx[i - 1]; mx[i - 1] = tmp; }
            }
        }
    }

    __shared__ float smn[256][RSEL];
    __shared__ float smx[256][RSEL];
#pragma unroll
    for (int i = 0; i < RSEL; ++i) { smn[tid][i] = mn[i]; smx[tid][i] = mx[i]; }

    for (int stride = 128; stride > 0; stride >>= 1) {
        __syncthreads();
        if (tid < stride) {
            float amn[RSEL], bmn[RSEL], omn[RSEL];
            float amx[RSEL], bmx[RSEL], omx[RSEL];
#pragma unroll
            for (int i = 0; i < RSEL; ++i) {
                amn[i] = smn[tid][i];  bmn[i] = smn[tid + stride][i];
                amx[i] = smx[tid][i];  bmx[i] = smx[tid + stride][i];
            }
            int ia = 0, ib = 0;  // 2-pointer merge: ia+ib == i <= RSEL-1, in-bounds
#pragma unroll
            for (int i = 0; i < RSEL; ++i)
                omn[i] = (amn[ia] <= bmn[ib]) ? amn[ia++] : bmn[ib++];
            ia = 0; ib = 0;
#pragma unroll
            for (int i = 0; i < RSEL; ++i)
                omx[i] = (amx[ia] >= bmx[ib]) ? amx[ia++] : bmx[ib++];
#pragma unroll
            for (int i = 0; i < RSEL; ++i) { smn[tid][i] = omn[i]; smx[tid][i] = omx[i]; }
        }
    }
    __syncthreads();

    // ---- MLP on this block's row ----
    __shared__ float x[2 * RSEL];
    __shared__ float h1[200];
    __shared__ float h2[100];
    if (tid < RSEL)                       x[tid] = smn[0][tid];                     // bottom-5 asc
    else if (tid < 2 * RSEL)              x[tid] = smx[0][2 * RSEL - 1 - tid];      // top-5 asc
    __syncthreads();

    if (tid < 200) {
        float acc = b1[tid];
#pragma unroll
        for (int i = 0; i < 2 * RSEL; ++i) acc += W1[tid * 2 * RSEL + i] * x[i];
        h1[tid] = 1.f / (1.f + expf(-acc));
    }
    __syncthreads();

    if (tid < 100) {
        float acc = b2[tid];
        for (int i = 0; i < 200; ++i) acc += W2[tid * 200 + i] * h1[i];
        h2[tid] = 1.f / (1.f + expf(-acc));
    }
    __syncthreads();

    if (tid == 0) {
        float acc = b3[0];
        for (int i = 0; i < 100; ++i) acc += W3[i] * h2[i];
        out[b]         = acc;                        // logits
        out[BATCH + b] = 1.f / (1.f + expf(-acc));   // probs
    }
}

extern "C" void kernel_launch(void* const* d_in, const int* in_sizes, int n_in,
                              void* d_out, int out_size, void* d_ws, size_t ws_size,
                              hipStream_t stream)
{
    const float* feats  = (const float*)d_in[0];
    const float* w_conv = (const float*)d_in[1];
    const float* W1     = (const float*)d_in[2];
    const float* b1     = (const float*)d_in[3];
    const float* W2     = (const float*)d_in[4];
    const float* b2     = (const float*)d_in[5];
    const float* W3     = (const float*)d_in[6];
    const float* b3     = (const float*)d_in[7];
    float* out = (float*)d_out;

    float* scores = (float*)d_ws;  // B*NTILES floats = 1 MB

    const int total_tiles = BATCH * NTILES;
    score_kernel<<<2048, 256, 0, stream>>>(feats, w_conv, scores, total_tiles);
    select_mlp_kernel<<<BATCH, 256, 0, stream>>>(scores, W1, b1, W2, b2, W3, b3, out);
}